// Round 5
// baseline (988.284 us; speedup 1.0000x reference)
//
#include <hip/hip_runtime.h>

#define N_NODES 50000
#define E1N 1600000
#define M_PAIRS 200000
#define E2N 3200000
#define P_OUT 20000
#define EPSF 1e-5f

#define RED_BLOCKS 512
#define SCAN_CHUNK 1024          // elements per scan block (256 thr x 4)
#define NB1 49                   // ceil(N_NODES/1024)
#define NB2 196                  // ceil(M_PAIRS/1024)

// ---------------- stats offsets within stats buffer (floats) ----------------
#define S0_SUM   0
#define S0_SQ    32
#define S_A0     64
#define S_B0ROW  96
#define S1_SUM   128
#define S1_SQ    160
#define S_A1     192
#define S_B1     224
#define S_CNT    256   // int
#define S_ZC0    288
#define S_ZC1    320
#define S3_SUM   352
#define S3_SQ    384
#define S_A3     416
#define S_B3     448
#define S_TOTAL  512

__device__ __forceinline__ void f4add(float4& a, const float4 b) {
    a.x += b.x; a.y += b.y; a.z += b.z; a.w += b.w;
}

// block-level reduce of per-thread float4 partials (feature group = (tid&7)*4),
// then one atomic per feature per block
__device__ __forceinline__ void stats_block_reduce(float4 s, float4 q,
                                                   float* __restrict__ sum,
                                                   float* __restrict__ sumsq) {
    __shared__ float4 ss[256], sq[256];
    int tid = threadIdx.x;
    ss[tid] = s; sq[tid] = q;
    __syncthreads();
    #pragma unroll
    for (int st = 128; st >= 8; st >>= 1) {
        if (tid < st) { f4add(ss[tid], ss[tid + st]); f4add(sq[tid], sq[tid + st]); }
        __syncthreads();
    }
    if (tid < 8) {
        int base = tid * 4;
        float4 fs = ss[tid], fq = sq[tid];
        atomicAdd(&sum[base + 0], fs.x);
        atomicAdd(&sum[base + 1], fs.y);
        atomicAdd(&sum[base + 2], fs.z);
        atomicAdd(&sum[base + 3], fs.w);
        atomicAdd(&sumsq[base + 0], fq.x);
        atomicAdd(&sumsq[base + 1], fq.y);
        atomicAdd(&sumsq[base + 2], fq.z);
        atomicAdd(&sumsq[base + 3], fq.w);
    }
}

// gather embedding rows (float4 granularity), store e, accumulate stats
__global__ void k_embed_stats(const float* __restrict__ emb, const int* __restrict__ x,
                              float* __restrict__ e, float* __restrict__ sum,
                              float* __restrict__ sumsq, int n) {
    long n4 = (long)n * 8;  // float4 count
    float4 s = {0,0,0,0}, q = {0,0,0,0};
    float4* e4 = (float4*)e;
    long stride = (long)gridDim.x * 256;
    for (long i = (long)blockIdx.x * 256 + threadIdx.x; i < n4; i += stride) {
        int node = (int)(i >> 3), fg = ((int)i & 7) * 4;
        int xr = x[node];
        float4 v = *(const float4*)&emb[(long)xr * 32 + fg];
        e4[i] = v;
        s.x += v.x; s.y += v.y; s.z += v.z; s.w += v.w;
        q.x += v.x * v.x; q.y += v.y * v.y; q.z += v.z * v.z; q.w += v.w * v.w;
    }
    stats_block_reduce(s, q, sum, sumsq);
}

// per-feature sum/sumsq over [n,32] buffer
__global__ void k_stats32(const float* __restrict__ g, float* __restrict__ sum,
                          float* __restrict__ sumsq, long n32) {
    long n4 = n32 >> 2;
    const float4* g4 = (const float4*)g;
    float4 s = {0,0,0,0}, q = {0,0,0,0};
    long stride = (long)gridDim.x * 256;
    for (long i = (long)blockIdx.x * 256 + threadIdx.x; i < n4; i += stride) {
        float4 v = g4[i];
        s.x += v.x; s.y += v.y; s.z += v.z; s.w += v.w;
        q.x += v.x * v.x; q.y += v.y * v.y; q.z += v.z * v.z; q.w += v.w * v.w;
    }
    stats_block_reduce(s, q, sum, sumsq);
}

// GraphNorm -> per-feature affine A,B.  y = A*x + B
__global__ void k_affine32(const float* __restrict__ sum, const float* __restrict__ sumsq,
                           const float* __restrict__ w, const float* __restrict__ b,
                           const float* __restrict__ ms, float invN,
                           float* __restrict__ A, float* __restrict__ B) {
    int f = threadIdx.x;  // 32 threads
    float mean = sum[f] * invN;
    float c = ms[f] * mean;
    float var = sumsq[f] * invN - 2.f * c * mean + c * c;
    float rs = rsqrtf(var + EPSF);
    A[f] = w[f] * rs;
    B[f] = b[f] - w[f] * rs * c;
}

// gn0 affine + fold shift through c1_W:  A[f], brow[o] = sum_f B[f]*W[f][o]
__global__ void k_affine_fold(const float* __restrict__ sum, const float* __restrict__ sumsq,
                              const float* __restrict__ w, const float* __restrict__ b,
                              const float* __restrict__ ms, float invN,
                              const float* __restrict__ W,
                              float* __restrict__ A, float* __restrict__ brow) {
    __shared__ float Bl[32];
    int f = threadIdx.x;  // 32 threads
    float mean = sum[f] * invN;
    float c = ms[f] * mean;
    float var = sumsq[f] * invN - 2.f * c * mean + c * c;
    float rs = rsqrtf(var + EPSF);
    A[f] = w[f] * rs;
    Bl[f] = b[f] - w[f] * rs * c;
    __syncthreads();
    float s = 0.f;
    #pragma unroll
    for (int f2 = 0; f2 < 32; f2++) s += Bl[f2] * W[f2 * 32 + f];
    brow[f] = s;
}

// t[i][o] = sum_f (A[f]*e[i][f]) * W[f][o] + brow[o]
__global__ void k_mm32(const float* __restrict__ e, const float* __restrict__ W,
                       const float* __restrict__ A, const float* __restrict__ brow,
                       float* __restrict__ t, int n) {
    __shared__ float Wp[32][32];
    __shared__ float rows[8][32];
    int lt = threadIdx.x;
    for (int k = lt; k < 1024; k += 256) {
        int f = k >> 5;
        Wp[f][k & 31] = A[f] * W[k];
    }
    int nl = lt >> 5, o = lt & 31;
    int node = blockIdx.x * 8 + nl;
    if (node < n) rows[nl][o] = e[(long)node * 32 + o];
    __syncthreads();
    if (node < n) {
        float acc = brow[o];
        #pragma unroll
        for (int f = 0; f < 32; f++) acc += rows[nl][f] * Wp[f][o];
        t[(long)node * 32 + o] = acc;
    }
}

// hw[i][o] = sum_f relu(A[f]*g[i][f]+B[f]) * W[f][o]   (fused gn1 affine+ReLU)
__global__ void k_mm32_relu_in(const float* __restrict__ g, const float* __restrict__ W,
                               const float* __restrict__ A, const float* __restrict__ B,
                               float* __restrict__ hw, int n) {
    __shared__ float Wp[32][32];
    __shared__ float rows[8][32];
    int lt = threadIdx.x;
    for (int k = lt; k < 1024; k += 256) {
        Wp[k >> 5][k & 31] = W[k];
    }
    int nl = lt >> 5, o = lt & 31;
    int node = blockIdx.x * 8 + nl;
    if (node < n) rows[nl][o] = fmaxf(A[o] * g[(long)node * 32 + o] + B[o], 0.f);
    __syncthreads();
    if (node < n) {
        float acc = 0.f;
        #pragma unroll
        for (int f = 0; f < 32; f++) acc += rows[nl][f] * Wp[f][o];
        hw[(long)node * 32 + o] = acc;
    }
}

// ---------------- CSR build ----------------

// counts for both graphs in one launch (int atomics; counts double as degrees)
__global__ void k_count_all(const int* __restrict__ e1col, const int* __restrict__ e2col,
                            int* __restrict__ c1, int* __restrict__ c2) {
    int i = blockIdx.x * 256 + threadIdx.x;
    if (i < E1N) atomicAdd(&c1[e1col[i]], 1);
    else if (i - E1N < E2N) atomicAdd(&c2[e2col[i - E1N]], 1);
}

// per-block sums for the scan (blocks [0,NB1) -> graph1, [NB1,NB1+NB2) -> graph2)
__global__ void k_scan_blk(const int* __restrict__ c1, const int* __restrict__ c2,
                           int* __restrict__ part1, int* __restrict__ part2) {
    int b = blockIdx.x;
    const int* arr; int n; int* part; int lb;
    if (b < NB1) { arr = c1; n = N_NODES; part = part1; lb = b; }
    else         { arr = c2; n = M_PAIRS; part = part2; lb = b - NB1; }
    int base = lb * SCAN_CHUNK + threadIdx.x * 4;
    int s = 0;
    #pragma unroll
    for (int u = 0; u < 4; u++) { int g = base + u; if (g < n) s += arr[g]; }
    __shared__ int sd[256];
    sd[threadIdx.x] = s;
    __syncthreads();
    for (int st = 128; st > 0; st >>= 1) {
        if (threadIdx.x < st) sd[threadIdx.x] += sd[threadIdx.x + st];
        __syncthreads();
    }
    if (threadIdx.x == 0) part[lb] = sd[0];
}

// exclusive scan of both partial arrays (single block)
__global__ void k_scan_top(int* __restrict__ part1, int* __restrict__ part2) {
    __shared__ int sd[256];
    int t = threadIdx.x;
    #pragma unroll
    for (int ph = 0; ph < 2; ph++) {
        int* part = ph ? part2 : part1;
        int nb = ph ? NB2 : NB1;
        int v = (t < nb) ? part[t] : 0;
        sd[t] = v;
        __syncthreads();
        for (int off = 1; off < 256; off <<= 1) {
            int a = (t >= off) ? sd[t - off] : 0;
            __syncthreads();
            sd[t] += a;
            __syncthreads();
        }
        if (t < nb) part[t] = sd[t] - v;  // exclusive
        __syncthreads();
    }
}

// write rowptr = block_offset + in-block exclusive scan; last element writes rowptr[n]
__global__ void k_scan_out(const int* __restrict__ c1, const int* __restrict__ c2,
                           const int* __restrict__ part1, const int* __restrict__ part2,
                           int* __restrict__ rp1, int* __restrict__ rp2) {
    int b = blockIdx.x;
    const int* arr; int n; const int* part; int* rp; int lb; int tot;
    if (b < NB1) { arr = c1; n = N_NODES; part = part1; rp = rp1; lb = b; tot = E1N; }
    else         { arr = c2; n = M_PAIRS; part = part2; rp = rp2; lb = b - NB1; tot = E2N; }
    int t = threadIdx.x;
    int base = lb * SCAN_CHUNK + t * 4;
    int v[4]; int s = 0;
    #pragma unroll
    for (int u = 0; u < 4; u++) { v[u] = (base + u < n) ? arr[base + u] : 0; s += v[u]; }
    __shared__ int sd[256];
    sd[t] = s;
    __syncthreads();
    for (int off = 1; off < 256; off <<= 1) {
        int a = (t >= off) ? sd[t - off] : 0;
        __syncthreads();
        sd[t] += a;
        __syncthreads();
    }
    int run = part[lb] + sd[t] - s;
    #pragma unroll
    for (int u = 0; u < 4; u++) {
        if (base + u < n) rp[base + u] = run;
        run += v[u];
    }
    if (n - 1 >= base && n - 1 < base + 4) rp[n] = tot;
}

// scatter edge source ids into CSR slots
__global__ void k_fill_all(const int* __restrict__ e1row, const int* __restrict__ e1col,
                           const int* __restrict__ e2row, const int* __restrict__ e2col,
                           const int* __restrict__ rp1, int* __restrict__ f1, int* __restrict__ csr1,
                           const int* __restrict__ rp2, int* __restrict__ f2, int* __restrict__ csr2) {
    int i = blockIdx.x * 256 + threadIdx.x;
    if (i < E1N) {
        int c = e1col[i];
        int p = rp1[c] + atomicAdd(&f1[c], 1);
        csr1[p] = e1row[i];
    } else if (i - E1N < E2N) {
        int j = i - E1N;
        int c = e2col[j];
        int p = rp2[c] + atomicAdd(&f2[c], 1);
        csr2[p] = e2row[j];
    }
}

// dinv from counts for both graphs
__global__ void k_dinv_all(const int* __restrict__ c1, float* __restrict__ d1,
                           const int* __restrict__ c2, float* __restrict__ d2) {
    int i = blockIdx.x * 256 + threadIdx.x;
    if (i < N_NODES) d1[i] = rsqrtf((float)c1[i] + 1.f);
    else if (i - N_NODES < M_PAIRS) {
        int j = i - N_NODES;
        d2[j] = rsqrtf((float)c2[j] + 1.f);
    }
}

// gather-sum GCN aggregation: one wave per dest node, 2 edges/iter, fused
// self-loop + conv bias.  agg[c] = (sum_e t[src]*dinv[src])*dinv[c] + t[c]*dinv[c]^2 + b
__global__ void k_gather(const int* __restrict__ rp, const int* __restrict__ csr,
                         const float* __restrict__ t, const float* __restrict__ dinv,
                         const float* __restrict__ bias, float* __restrict__ aggout, int n) {
    int wv = threadIdx.x >> 6;      // wave in block (0..3)
    int lane = threadIdx.x & 63;
    int half = lane >> 5, f = lane & 31;
    int node = blockIdx.x * 4 + wv;
    float acc = 0.f;
    int beg = 0, end = 0;
    if (node < n) { beg = rp[node]; end = rp[node + 1]; }
    for (int k = beg + half; k < end; k += 2) {
        int src = csr[k];
        acc += t[(long)src * 32 + f] * dinv[src];
    }
    acc += __shfl_xor(acc, 32);
    if (node < n && half == 0) {
        float dc = dinv[node];
        aggout[(long)node * 32 + f] = acc * dc + t[(long)node * 32 + f] * dc * dc + bias[f];
    }
}

__global__ void k_mask(const int* __restrict__ pos2, int* __restrict__ mask, int p) {
    int i = blockIdx.x * 256 + threadIdx.x;
    if (i < p) mask[pos2[i]] = 1;
}

__global__ void k_maskcnt(const int* __restrict__ mask, int* __restrict__ cnt, int m) {
    __shared__ int sd[256];
    int idx = blockIdx.x * 256 + threadIdx.x;
    sd[threadIdx.x] = (idx < m) ? mask[idx] : 0;
    __syncthreads();
    for (int s = 128; s > 0; s >>= 1) {
        if (threadIdx.x < s) sd[threadIdx.x] += sd[threadIdx.x + s];
        __syncthreads();
    }
    if (threadIdx.x == 0) atomicAdd(cnt, sd[0]);
}

// z has only two distinct rows (mask 0/1); compute zc{0,1}[o] = z{0,1} @ c2_W[32:48]
__global__ void k_zcalc(const float* __restrict__ emb2, const float* __restrict__ w,
                        const float* __restrict__ b, const float* __restrict__ ms,
                        const int* __restrict__ cnt, const float* __restrict__ c2W,
                        float* __restrict__ zc0, float* __restrict__ zc1) {
    __shared__ float z0[16], z1[16];
    int t = threadIdx.x;  // 32 threads
    const float Mf = (float)M_PAIRS;
    if (t < 16) {
        float e0 = emb2[t], e1 = emb2[16 + t];
        float c1f = (float)(*cnt);
        float mean = (c1f * e1 + (Mf - c1f) * e0) / Mf;
        float c = ms[t] * mean;
        float d0 = e0 - c, d1 = e1 - c;
        float var = (c1f * d1 * d1 + (Mf - c1f) * d0 * d0) / Mf;
        float rs = rsqrtf(var + EPSF);
        z0[t] = w[t] * d0 * rs + b[t];
        z1[t] = w[t] * d1 * rs + b[t];
    }
    __syncthreads();
    float s0 = 0.f, s1 = 0.f;
    #pragma unroll
    for (int f = 0; f < 16; f++) {
        float wv = c2W[(32 + f) * 32 + t];
        s0 += z0[f] * wv;
        s1 += z1[f] * wv;
    }
    zc0[t] = s0;
    zc1[t] = s1;
}

// t2[j][fg..] = hw[a][fg..] + hw[b][fg..] + zc_{mask[j]}[fg..]
__global__ void k_t2(const float* __restrict__ hw, const int* __restrict__ pos1,
                     const int* __restrict__ mask, const float* __restrict__ zc0,
                     const float* __restrict__ zc1, float* __restrict__ t2, int m) {
    long idx = (long)blockIdx.x * 256 + threadIdx.x;
    if (idx >= (long)m * 8) return;
    int j = (int)(idx >> 3), fg = ((int)idx & 7) * 4;
    int a = pos1[2 * j], b = pos1[2 * j + 1];
    const float* zc = mask[j] ? zc1 : zc0;
    float4 va = *(const float4*)&hw[(long)a * 32 + fg];
    float4 vb = *(const float4*)&hw[(long)b * 32 + fg];
    float4 vz = *(const float4*)&zc[fg];
    float4 r;
    r.x = va.x + vb.x + vz.x;
    r.y = va.y + vb.y + vz.y;
    r.z = va.z + vb.z + vz.z;
    r.w = va.w + vb.w + vz.w;
    *(float4*)&t2[idx * 4] = r;
}

// out[k] = relu(A*g2[pos2[k]]+B) . predW + predb
__global__ void k_pred(const float* __restrict__ g2, const int* __restrict__ pos2,
                       const float* __restrict__ A, const float* __restrict__ B,
                       const float* __restrict__ predW, const float* __restrict__ predb,
                       float* __restrict__ out, int p) {
    int k = blockIdx.x * 256 + threadIdx.x;
    if (k >= p) return;
    int j = pos2[k];
    float s = predb[0];
    #pragma unroll
    for (int o = 0; o < 32; o++)
        s += fmaxf(A[o] * g2[(long)j * 32 + o] + B[o], 0.f) * predW[o];
    out[k] = s;
}

extern "C" void kernel_launch(void* const* d_in, const int* in_sizes, int n_in,
                              void* d_out, int out_size, void* d_ws, size_t ws_size,
                              hipStream_t stream) {
    const int*   x      = (const int*)d_in[0];
    const int*   e1row  = (const int*)d_in[1];
    const int*   e1col  = e1row + E1N;
    const int*   e2row  = (const int*)d_in[2];
    const int*   e2col  = e2row + E2N;
    const int*   pos1   = (const int*)d_in[3];
    const int*   pos2   = (const int*)d_in[4];
    const float* emb1   = (const float*)d_in[5];
    const float* gn0_w  = (const float*)d_in[6];
    const float* gn0_b  = (const float*)d_in[7];
    const float* gn0_ms = (const float*)d_in[8];
    const float* c1_W   = (const float*)d_in[9];
    const float* c1_b   = (const float*)d_in[10];
    const float* gn1_w  = (const float*)d_in[11];
    const float* gn1_b  = (const float*)d_in[12];
    const float* gn1_ms = (const float*)d_in[13];
    const float* emb2   = (const float*)d_in[14];
    const float* gn2_w  = (const float*)d_in[15];
    const float* gn2_b  = (const float*)d_in[16];
    const float* gn2_ms = (const float*)d_in[17];
    const float* c2_W   = (const float*)d_in[18];
    const float* c2_b   = (const float*)d_in[19];
    const float* gn3_w  = (const float*)d_in[20];
    const float* gn3_b  = (const float*)d_in[21];
    const float* gn3_ms = (const float*)d_in[22];
    const float* predW  = (const float*)d_in[23];
    const float* predb  = (const float*)d_in[24];
    float* out = (float*)d_out;

    // ---------------- workspace arena (floats) ----------------
    const size_t N32 = (size_t)N_NODES * 32;   // 1,600,000
    const size_t M32 = (size_t)M_PAIRS * 32;   // 6,400,000
    float* fw = (float*)d_ws;
    size_t off = 0;
    auto alloc = [&](size_t n) { float* p = fw + off; off += n; return p; };
    float* e    = alloc(N32);            // also hw later
    float* t    = alloc(N32);
    float* agg  = alloc(N32);
    float* t2   = alloc(M32);            // csr1 aliases this (dead until k_t2)
    float* agg2 = alloc(M32);
    int*   csr2 = (int*)alloc(E2N);
    int*   rp1  = (int*)alloc(N_NODES + 1);
    int*   rp2  = (int*)alloc(M_PAIRS + 1);
    int*   part1 = (int*)alloc(256);
    int*   part2 = (int*)alloc(256);
    float* d1   = alloc(N_NODES);
    float* d2   = alloc(M_PAIRS);
    // ---- zero region (single memset): counts, fill cursors, mask, stats ----
    int*   c1   = (int*)alloc(N_NODES);
    int*   f1   = (int*)alloc(N_NODES);
    int*   c2i  = (int*)alloc(M_PAIRS);
    int*   f2i  = (int*)alloc(M_PAIRS);
    int*   mask = (int*)alloc(M_PAIRS);
    float* st   = alloc(S_TOTAL);
    int*   csr1 = (int*)t2;              // alias: csr1 live fill->gather1, t2 written after
    float* hw   = e;                     // alias: e dead after conv1 k_mm32

    const size_t zero_bytes = (2 * (size_t)N_NODES + 3 * (size_t)M_PAIRS + S_TOTAL) * 4;
    hipMemsetAsync(c1, 0, zero_bytes, stream);

    auto cdiv = [](long a, long b) { return (int)((a + b - 1) / b); };
    const float invN = 1.f / (float)N_NODES;
    const float invM = 1.f / (float)M_PAIRS;

    // ---- CSR build for both graphs ----
    k_count_all<<<cdiv((long)E1N + E2N, 256), 256, 0, stream>>>(e1col, e2col, c1, c2i);
    k_scan_blk<<<NB1 + NB2, 256, 0, stream>>>(c1, c2i, part1, part2);
    k_scan_top<<<1, 256, 0, stream>>>(part1, part2);
    k_scan_out<<<NB1 + NB2, 256, 0, stream>>>(c1, c2i, part1, part2, rp1, rp2);
    k_fill_all<<<cdiv((long)E1N + E2N, 256), 256, 0, stream>>>(e1row, e1col, e2row, e2col,
                                                               rp1, f1, csr1, rp2, f2i, csr2);
    k_dinv_all<<<cdiv((long)N_NODES + M_PAIRS, 256), 256, 0, stream>>>(c1, d1, c2i, d2);

    // ---- stage 0: embedding + gn0 stats ----
    k_embed_stats<<<RED_BLOCKS, 256, 0, stream>>>(emb1, x, e, st + S0_SUM, st + S0_SQ, N_NODES);
    k_affine_fold<<<1, 32, 0, stream>>>(st + S0_SUM, st + S0_SQ, gn0_w, gn0_b, gn0_ms, invN,
                                        c1_W, st + S_A0, st + S_B0ROW);

    // ---- conv1: t = gn0(e) @ c1_W ; gather ----
    k_mm32<<<cdiv(N_NODES, 8), 256, 0, stream>>>(e, c1_W, st + S_A0, st + S_B0ROW, t, N_NODES);
    k_gather<<<cdiv(N_NODES, 4), 256, 0, stream>>>(rp1, csr1, t, d1, c1_b, agg, N_NODES);

    // ---- gn1 stats; fused affine+relu inside hw matmul ----
    k_stats32<<<RED_BLOCKS, 256, 0, stream>>>(agg, st + S1_SUM, st + S1_SQ, (long)N32);
    k_affine32<<<1, 32, 0, stream>>>(st + S1_SUM, st + S1_SQ, gn1_w, gn1_b, gn1_ms, invN,
                                     st + S_A1, st + S_B1);
    k_mm32_relu_in<<<cdiv(N_NODES, 8), 256, 0, stream>>>(agg, c2_W, st + S_A1, st + S_B1,
                                                         hw, N_NODES);

    // ---- mask / z path ----
    k_mask<<<cdiv(P_OUT, 256), 256, 0, stream>>>(pos2, mask, P_OUT);
    k_maskcnt<<<cdiv(M_PAIRS, 256), 256, 0, stream>>>(mask, (int*)(st + S_CNT), M_PAIRS);
    k_zcalc<<<1, 32, 0, stream>>>(emb2, gn2_w, gn2_b, gn2_ms, (const int*)(st + S_CNT),
                                  c2_W, st + S_ZC0, st + S_ZC1);

    // ---- conv2 input rows; gather ----
    k_t2<<<cdiv((long)M_PAIRS * 8, 256), 256, 0, stream>>>(hw, pos1, mask, st + S_ZC0,
                                                           st + S_ZC1, t2, M_PAIRS);
    k_gather<<<cdiv(M_PAIRS, 4), 256, 0, stream>>>(rp2, csr2, t2, d2, c2_b, agg2, M_PAIRS);

    // ---- gn3 + relu + predict ----
    k_stats32<<<RED_BLOCKS, 256, 0, stream>>>(agg2, st + S3_SUM, st + S3_SQ, (long)M32);
    k_affine32<<<1, 32, 0, stream>>>(st + S3_SUM, st + S3_SQ, gn3_w, gn3_b, gn3_ms, invM,
                                     st + S_A3, st + S_B3);
    k_pred<<<cdiv(P_OUT, 256), 256, 0, stream>>>(agg2, pos2, st + S_A3, st + S_B3,
                                                 predW, predb, out, P_OUT);
}